// Round 7
// baseline (99.328 us; speedup 1.0000x reference)
//
#include <hip/hip_runtime.h>
#include <hip/hip_bf16.h>

#define CIN 128
#define COUT 256
#define H 56
#define W 56
#define OH 54
#define OW 54

typedef __attribute__((ext_vector_type(8))) short short8;
typedef __attribute__((ext_vector_type(4))) float floatx4;

typedef __attribute__((address_space(3))) unsigned int  lds_u32;
typedef const __attribute__((address_space(1))) unsigned int glb_u32;

static __device__ __forceinline__ unsigned short f2bf(float f) {
  unsigned int u = __builtin_bit_cast(unsigned int, f);
  u += 0x7fffu + ((u >> 16) & 1u);   // RNE
  return (unsigned short)(u >> 16);
}

// ---------- prepass 1: w[co][ci][kh][kw] f32 -> w2[k16][co][8] bf16 ----------
// k16 = (kh*3+kw)*16 + c8 ; ci = c8*8 + j
__global__ void repack_w(const float* __restrict__ w, unsigned short* __restrict__ w2) {
  int idx = blockIdx.x * 256 + threadIdx.x;
  if (idx >= COUT * CIN * 9) return;
  int kw = idx % 3, t1 = idx / 3;
  int kh = t1 % 3, t2 = t1 / 3;
  int ci = t2 % CIN;
  int co = t2 / CIN;
  int c8 = ci >> 3, j = ci & 7;
  w2[((((kh * 3 + kw) * 16 + c8) * COUT + co) * 8) + j] = f2bf(w[idx]);
}

// ---------- prepass 2: x NCHW f32 -> xb[n][h][g'] bf16, g' = iw*16 + (c16 ^ (iw&7)) ----
__global__ void repack_x(const float* __restrict__ x, unsigned short* __restrict__ xb) {
  int t = blockIdx.x * 256 + threadIdx.x;   // 32*56*16*56 = 1,605,632 = 6272*256
  int iw = t % 56, t1 = t / 56;
  int c16 = t1 & 15, t2 = t1 >> 4;
  int h = t2 % 56, n = t2 / 56;
  const float* xp = x + (((size_t)n * CIN + c16 * 8) * H + h) * W + iw;
  short8 v;
  #pragma unroll
  for (int j = 0; j < 8; ++j)
    v[j] = (short)f2bf(xp[(size_t)j * (H * W)]);
  int gp = iw * 16 + (c16 ^ (iw & 7));
  *reinterpret_cast<short8*>(&xb[(((size_t)n * H + h) * 896 + gp) * 8]) = v;
}

// ---------- main conv: 8 waves = 4 co-groups x 2 rows; wave = 64co x 64px ----------
// launch_bounds(512,2): 256-reg budget -> acc(64) + areg[3][4](96) + b(32) + addr fits.
__global__ __launch_bounds__(512, 2) void conv2(
    const unsigned short* __restrict__ xb, const unsigned short* __restrict__ w2,
    const float* __restrict__ bias, float* __restrict__ out) {
  // 4 rows x 896 granules + 160-granule overrun pad (garbage px>=54 reads) = 59,904 B
  __shared__ alignas(16) unsigned short xs[3744 * 8];

  // XCD-bijective swizzle: 864 % 8 == 0
  const int f = blockIdx.x;
  const int swz = (f & 7) * 108 + (f >> 3);
  const int ohp = swz % 27;
  const int n   = swz / 27;
  const int oh0 = ohp * 2;
  const int tid = threadIdx.x;
  const int wid  = tid >> 6;
  const int lane = tid & 63;

  // ---- stage 4 contiguous rows (3584 granules) via global_load_lds, 7/thread ----
  {
    const unsigned short* src = xb + ((size_t)n * H + oh0) * 896 * 8;
    #pragma unroll
    for (int i = 0; i < 7; ++i) {
      int idx = (wid * 7 + i) * 64;                 // wave-uniform granule base
      __builtin_amdgcn_global_load_lds(
          (glb_u32*)(src + (size_t)(idx + lane) * 8),
          (lds_u32*)(&xs[idx * 8]), 16, 0, 0);
    }
  }
  asm volatile("s_waitcnt vmcnt(0)" ::: "memory");
  __syncthreads();

  const int wm   = wid >> 1;       // co group (0..3) -> 64 couts
  const int wn   = wid & 1;        // output row within the pair
  const int l16  = lane & 15;
  const int cig  = lane >> 4;      // 0..3

  const int co_base = wm * 64;
  const int oh = oh0 + wn;

  floatx4 acc[4][4];
  #pragma unroll
  for (int m = 0; m < 4; ++m)
    #pragma unroll
    for (int nr = 0; nr < 4; ++nr)
      acc[m][nr] = (floatx4){0.f, 0.f, 0.f, 0.f};

  // A-fragment loader for flat k-step ks = kh*12 + ch*3 + kw
#define ALOAD(ks, dst)                                                          \
  {                                                                             \
    const int kh_ = (ks) / 12, ch_ = ((ks) / 3) & 3, kw_ = (ks) % 3;            \
    const unsigned short* wp_ = w2 +                                            \
        ((size_t)(((kh_ * 3 + kw_) * 16 + (ch_ * 4 + cig)) * COUT + co_base + l16)) * 8; \
    (dst)[0] = *reinterpret_cast<const short8*>(wp_);                           \
    (dst)[1] = *reinterpret_cast<const short8*>(wp_ + 128);                     \
    (dst)[2] = *reinterpret_cast<const short8*>(wp_ + 256);                     \
    (dst)[3] = *reinterpret_cast<const short8*>(wp_ + 384);                     \
  }

  // ---- software-pipelined K-loop: depth-2 A-prefetch (3 slots, %3 is static) ----
  short8 areg[3][4];
  ALOAD(0, areg[0]);
  ALOAD(1, areg[1]);
  #pragma unroll
  for (int ks = 0; ks < 36; ++ks) {
    if (ks < 34) ALOAD(ks + 2, areg[(ks + 2) % 3]);   // 2 steps in flight
    const int kh = ks / 12, ch = (ks / 3) & 3, kw = ks % 3;
    const int row = wn + kh;
    const int iwl = l16 + kw;
    const int c16x = (ch * 4 + cig) ^ (iwl & 7);
    const int boff = (row * 896 + iwl * 16 + c16x) * 8;   // ushort index
    short8 b[4];
    #pragma unroll
    for (int nr = 0; nr < 4; ++nr)
      b[nr] = *reinterpret_cast<const short8*>(&xs[boff + nr * 2048]);
    #pragma unroll
    for (int m = 0; m < 4; ++m)
      #pragma unroll
      for (int nr = 0; nr < 4; ++nr)
        acc[m][nr] = __builtin_amdgcn_mfma_f32_16x16x32_bf16(
            areg[ks % 3][m], b[nr], acc[m][nr], 0, 0, 0);
  }
#undef ALOAD

  // ---- epilogue: C/D layout col=lane&15, row=(lane>>4)*4+reg ----
  const int rowd = cig * 4;
  #pragma unroll
  for (int m = 0; m < 4; ++m) {
    #pragma unroll
    for (int reg = 0; reg < 4; ++reg) {
      int co = co_base + m * 16 + rowd + reg;
      float bv = bias[co];
      float* op = out + (((size_t)n * COUT + co) * OH + oh) * OW;
      #pragma unroll
      for (int nr = 0; nr < 4; ++nr) {
        int ow = nr * 16 + l16;
        if (ow < OW) op[ow] = acc[m][nr][reg] + bv;
      }
    }
  }
}

// ================== fallback path (ws too small): round-2 kernel ==================
#define CSTR 136
#define IWP 66

__global__ __launch_bounds__(512, 4) void conv_fb(
    const float* __restrict__ x, const unsigned short* __restrict__ w2,
    const float* __restrict__ bias, float* __restrict__ out) {
  __shared__ alignas(16) unsigned short xsf[4 * IWP * CSTR];

  const int ohp = blockIdx.x;
  const int n   = blockIdx.y;
  const int oh0 = ohp * 2;
  const int tid = threadIdx.x;

  {
    short8 zz = {0, 0, 0, 0, 0, 0, 0, 0};
    for (int i = tid; i < 4 * 10 * 17; i += 512) {
      int r = i / 170, rem = i % 170;
      int iw = 56 + rem / 17, g = rem % 17;
      *reinterpret_cast<short8*>(&xsf[(r * IWP + iw) * CSTR + g * 8]) = zz;
    }
  }
  for (int s = tid; s < 3584; s += 512) {
    int iw = s % 56;
    int t  = s / 56;
    int c8 = t & 15, r = t >> 4;
    const float* xp = x + (size_t)n * CIN * (H * W) + (oh0 + r) * W + iw;
    short8 v;
    #pragma unroll
    for (int j = 0; j < 8; ++j)
      v[j] = (short)f2bf(xp[(size_t)(c8 * 8 + j) * (H * W)]);
    *reinterpret_cast<short8*>(&xsf[(r * IWP + iw) * CSTR + c8 * 8]) = v;
  }
  __syncthreads();

  const int wid  = tid >> 6;
  const int lane = tid & 63;
  const int wm   = wid >> 1;
  const int wn   = wid & 1;
  const int l16  = lane & 15;
  const int cig  = lane >> 4;

  const int co_base = wm * 64;
  const int oh = oh0 + wn;

  floatx4 acc[4][4];
  #pragma unroll
  for (int m = 0; m < 4; ++m)
    #pragma unroll
    for (int nr = 0; nr < 4; ++nr)
      acc[m][nr] = (floatx4){0.f, 0.f, 0.f, 0.f};

  for (int kh = 0; kh < 3; ++kh) {
    const int row = wn + kh;
    #pragma unroll
    for (int ch = 0; ch < 4; ++ch) {
      const int bbase = (row * IWP + l16) * CSTR + ch * 32 + cig * 8;
      #pragma unroll
      for (int kw = 0; kw < 3; ++kw) {
        const unsigned short* wp =
            w2 + ((size_t)(((kh * 3 + kw) * 16 + (ch * 4 + cig)) * COUT + co_base + l16)) * 8;
        short8 a[4];
        #pragma unroll
        for (int m = 0; m < 4; ++m)
          a[m] = *reinterpret_cast<const short8*>(wp + m * 16 * 8);
        short8 b[4];
        #pragma unroll
        for (int nr = 0; nr < 4; ++nr)
          b[nr] = *reinterpret_cast<const short8*>(&xsf[bbase + (nr * 16 + kw) * CSTR]);
        #pragma unroll
        for (int m = 0; m < 4; ++m)
          #pragma unroll
          for (int nr = 0; nr < 4; ++nr)
            acc[m][nr] = __builtin_amdgcn_mfma_f32_16x16x32_bf16(a[m], b[nr], acc[m][nr], 0, 0, 0);
      }
    }
  }

  const int rowd = cig * 4;
  #pragma unroll
  for (int m = 0; m < 4; ++m) {
    #pragma unroll
    for (int reg = 0; reg < 4; ++reg) {
      int co = co_base + m * 16 + rowd + reg;
      float bv = bias[co];
      float* op = out + (((size_t)n * COUT + co) * OH + oh) * OW;
      #pragma unroll
      for (int nr = 0; nr < 4; ++nr) {
        int ow = nr * 16 + l16;
        if (ow < OW) op[ow] = acc[m][nr][reg] + bv;
      }
    }
  }
}

extern "C" void kernel_launch(void* const* d_in, const int* in_sizes, int n_in,
                              void* d_out, int out_size, void* d_ws, size_t ws_size,
                              hipStream_t stream) {
  (void)in_sizes; (void)n_in; (void)out_size;
  const float* x    = (const float*)d_in[0];
  const float* w    = (const float*)d_in[1];
  const float* bias = (const float*)d_in[2];
  float* out = (float*)d_out;

  const size_t W2_BYTES = (size_t)9 * 16 * COUT * 8 * 2;            // 589,824
  const size_t XB_BYTES = (size_t)32 * H * 896 * 8 * 2;             // 25,690,112
  unsigned short* w2 = (unsigned short*)d_ws;

  repack_w<<<dim3((COUT * CIN * 9 + 255) / 256), dim3(256), 0, stream>>>(w, w2);

  if (ws_size >= W2_BYTES + XB_BYTES) {
    unsigned short* xb = (unsigned short*)((char*)d_ws + W2_BYTES);
    repack_x<<<dim3(6272), dim3(256), 0, stream>>>(x, xb);
    conv2<<<dim3(864), dim3(512), 0, stream>>>(xb, w2, bias, out);
  } else {
    conv_fb<<<dim3(27, 32), dim3(512), 0, stream>>>(x, w2, bias, out);
  }
}

// Round 8
// 97.989 us; speedup vs baseline: 1.0137x; 1.0137x over previous
//
#include <hip/hip_runtime.h>
#include <hip/hip_bf16.h>

#define CIN 128
#define COUT 256
#define H 56
#define W 56
#define OH 54
#define OW 54

typedef __attribute__((ext_vector_type(8))) short short8;
typedef __attribute__((ext_vector_type(4))) float floatx4;

typedef __attribute__((address_space(3))) unsigned int  lds_u32;
typedef const __attribute__((address_space(1))) unsigned int glb_u32;

static __device__ __forceinline__ unsigned short f2bf(float f) {
  unsigned int u = __builtin_bit_cast(unsigned int, f);
  u += 0x7fffu + ((u >> 16) & 1u);   // RNE
  return (unsigned short)(u >> 16);
}

// ---------- prepass 1: w[co][ci][kh][kw] f32 -> w2[k16][co][8] bf16 ----------
// k16 = (kh*3+kw)*16 + c8 ; ci = c8*8 + j
__global__ void repack_w(const float* __restrict__ w, unsigned short* __restrict__ w2) {
  int idx = blockIdx.x * 256 + threadIdx.x;
  if (idx >= COUT * CIN * 9) return;
  int kw = idx % 3, t1 = idx / 3;
  int kh = t1 % 3, t2 = t1 / 3;
  int ci = t2 % CIN;
  int co = t2 / CIN;
  int c8 = ci >> 3, j = ci & 7;
  w2[((((kh * 3 + kw) * 16 + c8) * COUT + co) * 8) + j] = f2bf(w[idx]);
}

// ---------- prepass 2: x NCHW f32 -> xb[n][h][g'] bf16, g' = iw*16 + (c16 ^ (iw&7)) ----
__global__ void repack_x(const float* __restrict__ x, unsigned short* __restrict__ xb) {
  int t = blockIdx.x * 256 + threadIdx.x;   // 32*56*16*56 = 1,605,632 = 6272*256
  int iw = t % 56, t1 = t / 56;
  int c16 = t1 & 15, t2 = t1 >> 4;
  int h = t2 % 56, n = t2 / 56;
  const float* xp = x + (((size_t)n * CIN + c16 * 8) * H + h) * W + iw;
  short8 v;
  #pragma unroll
  for (int j = 0; j < 8; ++j)
    v[j] = (short)f2bf(xp[(size_t)j * (H * W)]);
  int gp = iw * 16 + (c16 ^ (iw & 7));
  *reinterpret_cast<short8*>(&xb[(((size_t)n * H + h) * 896 + gp) * 8]) = v;
}

// ---------- main conv: 8 waves = 4 co-groups x 2 rows; wave = 64co x 64px ----------
// Depth-1 A-prefetch pinned by memory-clobber fences: the scheduler cannot sink
// loads across an asm memory barrier, so each step's A-loads issue one full
// k-step before their consuming MFMAs (compiler emits counted vmcnt(4)).
__global__ __launch_bounds__(512, 2) void conv2(
    const unsigned short* __restrict__ xb, const unsigned short* __restrict__ w2,
    const float* __restrict__ bias, float* __restrict__ out) {
  // 4 rows x 896 granules + 160-granule overrun pad (garbage px>=54 reads) = 59,904 B
  __shared__ alignas(16) unsigned short xs[3744 * 8];

  // XCD-bijective swizzle: 864 % 8 == 0
  const int f = blockIdx.x;
  const int swz = (f & 7) * 108 + (f >> 3);
  const int ohp = swz % 27;
  const int n   = swz / 27;
  const int oh0 = ohp * 2;
  const int tid = threadIdx.x;
  const int wid  = tid >> 6;
  const int lane = tid & 63;

  // ---- stage 4 contiguous rows (3584 granules) via global_load_lds, 7/thread ----
  {
    const unsigned short* src = xb + ((size_t)n * H + oh0) * 896 * 8;
    #pragma unroll
    for (int i = 0; i < 7; ++i) {
      int idx = (wid * 7 + i) * 64;                 // wave-uniform granule base
      __builtin_amdgcn_global_load_lds(
          (glb_u32*)(src + (size_t)(idx + lane) * 8),
          (lds_u32*)(&xs[idx * 8]), 16, 0, 0);
    }
  }
  asm volatile("s_waitcnt vmcnt(0)" ::: "memory");
  __syncthreads();

  const int wm   = wid >> 1;       // co group (0..3) -> 64 couts
  const int wn   = wid & 1;        // output row within the pair
  const int l16  = lane & 15;
  const int cig  = lane >> 4;      // 0..3

  const int co_base = wm * 64;
  const int oh = oh0 + wn;

  floatx4 acc[4][4];
  #pragma unroll
  for (int m = 0; m < 4; ++m)
    #pragma unroll
    for (int nr = 0; nr < 4; ++nr)
      acc[m][nr] = (floatx4){0.f, 0.f, 0.f, 0.f};

  // A-fragment loader for flat k-step ks = kh*12 + ch*3 + kw
#define ALOAD(ks, dst)                                                          \
  {                                                                             \
    const int kh_ = (ks) / 12, ch_ = ((ks) / 3) & 3, kw_ = (ks) % 3;            \
    const unsigned short* wp_ = w2 +                                            \
        ((size_t)(((kh_ * 3 + kw_) * 16 + (ch_ * 4 + cig)) * COUT + co_base + l16)) * 8; \
    (dst)[0] = *reinterpret_cast<const short8*>(wp_);                           \
    (dst)[1] = *reinterpret_cast<const short8*>(wp_ + 128);                     \
    (dst)[2] = *reinterpret_cast<const short8*>(wp_ + 256);                     \
    (dst)[3] = *reinterpret_cast<const short8*>(wp_ + 384);                     \
  }

  // ---- K-loop with fence-pinned depth-1 A-prefetch ----
  short8 areg[2][4];
  ALOAD(0, areg[0]);
  asm volatile("" ::: "memory");     // pin prologue load issue
  #pragma unroll
  for (int ks = 0; ks < 36; ++ks) {
    if (ks < 35) {
      ALOAD(ks + 1, areg[(ks + 1) & 1]);   // issue next step's A-loads NOW
      asm volatile("" ::: "memory");       // loads may not sink below this point
    }
    const int kh = ks / 12, ch = (ks / 3) & 3, kw = ks % 3;
    const int row = wn + kh;
    const int iwl = l16 + kw;
    const int c16x = (ch * 4 + cig) ^ (iwl & 7);
    const int boff = (row * 896 + iwl * 16 + c16x) * 8;   // ushort index
    short8 b[4];
    #pragma unroll
    for (int nr = 0; nr < 4; ++nr)
      b[nr] = *reinterpret_cast<const short8*>(&xs[boff + nr * 2048]);
    #pragma unroll
    for (int m = 0; m < 4; ++m)
      #pragma unroll
      for (int nr = 0; nr < 4; ++nr)
        acc[m][nr] = __builtin_amdgcn_mfma_f32_16x16x32_bf16(
            areg[ks & 1][m], b[nr], acc[m][nr], 0, 0, 0);
  }
#undef ALOAD

  // ---- epilogue: C/D layout col=lane&15, row=(lane>>4)*4+reg ----
  const int rowd = cig * 4;
  #pragma unroll
  for (int m = 0; m < 4; ++m) {
    #pragma unroll
    for (int reg = 0; reg < 4; ++reg) {
      int co = co_base + m * 16 + rowd + reg;
      float bv = bias[co];
      float* op = out + (((size_t)n * COUT + co) * OH + oh) * OW;
      #pragma unroll
      for (int nr = 0; nr < 4; ++nr) {
        int ow = nr * 16 + l16;
        if (ow < OW) op[ow] = acc[m][nr][reg] + bv;
      }
    }
  }
}

// ================== fallback path (ws too small): round-2 kernel ==================
#define CSTR 136
#define IWP 66

__global__ __launch_bounds__(512, 4) void conv_fb(
    const float* __restrict__ x, const unsigned short* __restrict__ w2,
    const float* __restrict__ bias, float* __restrict__ out) {
  __shared__ alignas(16) unsigned short xsf[4 * IWP * CSTR];

  const int ohp = blockIdx.x;
  const int n   = blockIdx.y;
  const int oh0 = ohp * 2;
  const int tid = threadIdx.x;

  {
    short8 zz = {0, 0, 0, 0, 0, 0, 0, 0};
    for (int i = tid; i < 4 * 10 * 17; i += 512) {
      int r = i / 170, rem = i % 170;
      int iw = 56 + rem / 17, g = rem % 17;
      *reinterpret_cast<short8*>(&xsf[(r * IWP + iw) * CSTR + g * 8]) = zz;
    }
  }
  for (int s = tid; s < 3584; s += 512) {
    int iw = s % 56;
    int t  = s / 56;
    int c8 = t & 15, r = t >> 4;
    const float* xp = x + (size_t)n * CIN * (H * W) + (oh0 + r) * W + iw;
    short8 v;
    #pragma unroll
    for (int j = 0; j < 8; ++j)
      v[j] = (short)f2bf(xp[(size_t)(c8 * 8 + j) * (H * W)]);
    *reinterpret_cast<short8*>(&xsf[(r * IWP + iw) * CSTR + c8 * 8]) = v;
  }
  __syncthreads();

  const int wid  = tid >> 6;
  const int lane = tid & 63;
  const int wm   = wid >> 1;
  const int wn   = wid & 1;
  const int l16  = lane & 15;
  const int cig  = lane >> 4;

  const int co_base = wm * 64;
  const int oh = oh0 + wn;

  floatx4 acc[4][4];
  #pragma unroll
  for (int m = 0; m < 4; ++m)
    #pragma unroll
    for (int nr = 0; nr < 4; ++nr)
      acc[m][nr] = (floatx4){0.f, 0.f, 0.f, 0.f};

  for (int kh = 0; kh < 3; ++kh) {
    const int row = wn + kh;
    #pragma unroll
    for (int ch = 0; ch < 4; ++ch) {
      const int bbase = (row * IWP + l16) * CSTR + ch * 32 + cig * 8;
      #pragma unroll
      for (int kw = 0; kw < 3; ++kw) {
        const unsigned short* wp =
            w2 + ((size_t)(((kh * 3 + kw) * 16 + (ch * 4 + cig)) * COUT + co_base + l16)) * 8;
        short8 a[4];
        #pragma unroll
        for (int m = 0; m < 4; ++m)
          a[m] = *reinterpret_cast<const short8*>(wp + m * 16 * 8);
        short8 b[4];
        #pragma unroll
        for (int nr = 0; nr < 4; ++nr)
          b[nr] = *reinterpret_cast<const short8*>(&xsf[bbase + (nr * 16 + kw) * CSTR]);
        #pragma unroll
        for (int m = 0; m < 4; ++m)
          #pragma unroll
          for (int nr = 0; nr < 4; ++nr)
            acc[m][nr] = __builtin_amdgcn_mfma_f32_16x16x32_bf16(a[m], b[nr], acc[m][nr], 0, 0, 0);
      }
    }
  }

  const int rowd = cig * 4;
  #pragma unroll
  for (int m = 0; m < 4; ++m) {
    #pragma unroll
    for (int reg = 0; reg < 4; ++reg) {
      int co = co_base + m * 16 + rowd + reg;
      float bv = bias[co];
      float* op = out + (((size_t)n * COUT + co) * OH + oh) * OW;
      #pragma unroll
      for (int nr = 0; nr < 4; ++nr) {
        int ow = nr * 16 + l16;
        if (ow < OW) op[ow] = acc[m][nr][reg] + bv;
      }
    }
  }
}

extern "C" void kernel_launch(void* const* d_in, const int* in_sizes, int n_in,
                              void* d_out, int out_size, void* d_ws, size_t ws_size,
                              hipStream_t stream) {
  (void)in_sizes; (void)n_in; (void)out_size;
  const float* x    = (const float*)d_in[0];
  const float* w    = (const float*)d_in[1];
  const float* bias = (const float*)d_in[2];
  float* out = (float*)d_out;

  const size_t W2_BYTES = (size_t)9 * 16 * COUT * 8 * 2;            // 589,824
  const size_t XB_BYTES = (size_t)32 * H * 896 * 8 * 2;             // 25,690,112
  unsigned short* w2 = (unsigned short*)d_ws;

  repack_w<<<dim3((COUT * CIN * 9 + 255) / 256), dim3(256), 0, stream>>>(w, w2);

  if (ws_size >= W2_BYTES + XB_BYTES) {
    unsigned short* xb = (unsigned short*)((char*)d_ws + W2_BYTES);
    repack_x<<<dim3(6272), dim3(256), 0, stream>>>(x, xb);
    conv2<<<dim3(864), dim3(512), 0, stream>>>(xb, w2, bias, out);
  } else {
    conv_fb<<<dim3(27, 32), dim3(512), 0, stream>>>(x, w2, bias, out);
  }
}

// Round 10
// 92.603 us; speedup vs baseline: 1.0726x; 1.0582x over previous
//
#include <hip/hip_runtime.h>
#include <hip/hip_bf16.h>

#define CIN 128
#define COUT 256
#define H 56
#define W 56
#define OH 54
#define OW 54

typedef __attribute__((ext_vector_type(8))) short short8;
typedef __attribute__((ext_vector_type(4))) float floatx4;

typedef __attribute__((address_space(3))) unsigned int  lds_u32;
typedef const __attribute__((address_space(1))) unsigned int glb_u32;

static __device__ __forceinline__ unsigned short f2bf(float f) {
  unsigned int u = __builtin_bit_cast(unsigned int, f);
  u += 0x7fffu + ((u >> 16) & 1u);   // RNE
  return (unsigned short)(u >> 16);
}

// ---------- prepass 1: w[co][ci][kh][kw] f32 -> w2[k16][co][8] bf16 ----------
__global__ void repack_w(const float* __restrict__ w, unsigned short* __restrict__ w2) {
  int idx = blockIdx.x * 256 + threadIdx.x;
  if (idx >= COUT * CIN * 9) return;
  int kw = idx % 3, t1 = idx / 3;
  int kh = t1 % 3, t2 = t1 / 3;
  int ci = t2 % CIN;
  int co = t2 / CIN;
  int c8 = ci >> 3, j = ci & 7;
  w2[((((kh * 3 + kw) * 16 + c8) * COUT + co) * 8) + j] = f2bf(w[idx]);
}

// ---------- prepass 2 (LDS transpose, coalesced both sides) ----------
// x NCHW f32 -> xb[n][h][g'] bf16, g' = iw*16 + (c16 ^ (iw&7)).
__global__ __launch_bounds__(256) void repack_x(const float* __restrict__ x,
                                                unsigned short* __restrict__ xb) {
  __shared__ float xt[56][129];   // 129 odd: phase-1 banks spread, 28,896 B
  const int h = blockIdx.x;       // 0..55
  const int n = blockIdx.y;       // 0..31
  const float* src = x + (size_t)n * CIN * (H * W) + h * W;   // + ci*3136 + iw
  // phase 1: 7168 floats, coalesced global reads
  #pragma unroll
  for (int r = 0; r < 28; ++r) {
    int idx = r * 256 + threadIdx.x;
    int ci = idx / 56, iw = idx % 56;
    xt[iw][ci] = src[ci * (H * W) + iw];
  }
  __syncthreads();
  // phase 2: 896 granules; consecutive threads -> consecutive c16 -> contiguous writes
  unsigned short* dst = xb + ((size_t)n * H + h) * 896 * 8;
  #pragma unroll
  for (int r = 0; r < 4; ++r) {
    int g = r * 256 + threadIdx.x;
    if (g < 896) {
      int iw = g >> 4, c16 = g & 15;
      short8 v;
      #pragma unroll
      for (int j = 0; j < 8; ++j)
        v[j] = (short)f2bf(xt[iw][c16 * 8 + j]);
      int gp = iw * 16 + (c16 ^ (iw & 7));
      *reinterpret_cast<short8*>(&dst[gp * 8]) = v;
    }
  }
}

// ---------- main conv: 8 waves = 4 co-groups x 2 rows; wave = 64co x 64px ----------
// Enforced software pipeline: loads(s+1) -> sched_barrier(0) -> MFMA(s).
__global__ __launch_bounds__(512, 2) void conv2(
    const unsigned short* __restrict__ xb, const unsigned short* __restrict__ w2,
    const float* __restrict__ bias, float* __restrict__ out) {
  __shared__ alignas(16) unsigned short xs[3744 * 8];  // 4 rows x 896 g + pad

  // XCD-bijective swizzle: 864 % 8 == 0
  const int f = blockIdx.x;
  const int swz = (f & 7) * 108 + (f >> 3);
  const int ohp = swz % 27;
  const int n   = swz / 27;
  const int oh0 = ohp * 2;
  const int tid = threadIdx.x;
  const int wid  = tid >> 6;
  const int lane = tid & 63;

  // ---- stage 4 contiguous rows (3584 granules) via global_load_lds ----
  {
    const unsigned short* src = xb + ((size_t)n * H + oh0) * 896 * 8;
    #pragma unroll
    for (int i = 0; i < 7; ++i) {
      int idx = (wid * 7 + i) * 64;
      __builtin_amdgcn_global_load_lds(
          (glb_u32*)(src + (size_t)(idx + lane) * 8),
          (lds_u32*)(&xs[idx * 8]), 16, 0, 0);
    }
  }
  asm volatile("s_waitcnt vmcnt(0)" ::: "memory");
  __syncthreads();

  const int wm   = wid >> 1;       // co group (0..3)
  const int wn   = wid & 1;        // output row within the pair
  const int l16  = lane & 15;
  const int cig  = lane >> 4;      // 0..3

  const int co_base = wm * 64;
  const int oh = oh0 + wn;

  // per-wave precomputed bases
  const unsigned short* wbase = w2 + ((size_t)(cig * COUT + co_base + l16)) * 8;
  const int bwn = wn * 896 * 8;                 // row base (ushort idx)
  int ib[3], x7[3];
  #pragma unroll
  for (int kw = 0; kw < 3; ++kw) {
    ib[kw] = (l16 + kw) * 16 * 8;
    x7[kw] = (l16 + kw) & 7;
  }

  floatx4 acc[4][4];
  #pragma unroll
  for (int m = 0; m < 4; ++m)
    #pragma unroll
    for (int nr = 0; nr < 4; ++nr)
      acc[m][nr] = (floatx4){0.f, 0.f, 0.f, 0.f};

  short8 areg[2][4], breg[2][4];

  // load A+B fragments for flat step s = kh*12 + ch*3 + kw into slot
  // (const, not constexpr: folded to constants after full unroll)
#define STEP_LOAD(s, slot)                                                      \
  {                                                                             \
    const int kh_ = (s) / 12, ch_ = ((s) / 3) & 3, kw_ = (s) % 3;               \
    const unsigned short* wp_ =                                                 \
        wbase + (size_t)(((kh_ * 3 + kw_) * 16 + ch_ * 4) * COUT) * 8;          \
    areg[slot][0] = *reinterpret_cast<const short8*>(wp_);                      \
    areg[slot][1] = *reinterpret_cast<const short8*>(wp_ + 128);                \
    areg[slot][2] = *reinterpret_cast<const short8*>(wp_ + 256);                \
    areg[slot][3] = *reinterpret_cast<const short8*>(wp_ + 384);                \
    const int c16x_ = (ch_ * 4 + cig) ^ x7[kw_];                                \
    const int boff_ = bwn + kh_ * (896 * 8) + ib[kw_] + c16x_ * 8;              \
    breg[slot][0] = *reinterpret_cast<const short8*>(&xs[boff_]);               \
    breg[slot][1] = *reinterpret_cast<const short8*>(&xs[boff_ + 2048]);        \
    breg[slot][2] = *reinterpret_cast<const short8*>(&xs[boff_ + 4096]);        \
    breg[slot][3] = *reinterpret_cast<const short8*>(&xs[boff_ + 6144]);        \
  }

  STEP_LOAD(0, 0);
  #pragma unroll
  for (int s = 0; s < 36; ++s) {
    if (s < 35) STEP_LOAD(s + 1, (s + 1) & 1);
    __builtin_amdgcn_sched_barrier(0);   // loads(s+1) may not sink; MFMA(s) may not hoist
    __builtin_amdgcn_s_setprio(1);
    #pragma unroll
    for (int m = 0; m < 4; ++m)
      #pragma unroll
      for (int nr = 0; nr < 4; ++nr)
        acc[m][nr] = __builtin_amdgcn_mfma_f32_16x16x32_bf16(
            areg[s & 1][m], breg[s & 1][nr], acc[m][nr], 0, 0, 0);
    __builtin_amdgcn_s_setprio(0);
  }
#undef STEP_LOAD

  // ---- epilogue: C/D layout col=lane&15, row=(lane>>4)*4+reg ----
  const int rowd = cig * 4;
  #pragma unroll
  for (int m = 0; m < 4; ++m) {
    #pragma unroll
    for (int reg = 0; reg < 4; ++reg) {
      int co = co_base + m * 16 + rowd + reg;
      float bv = bias[co];
      float* op = out + (((size_t)n * COUT + co) * OH + oh) * OW;
      #pragma unroll
      for (int nr = 0; nr < 4; ++nr) {
        int ow = nr * 16 + l16;
        if (ow < OW) op[ow] = acc[m][nr][reg] + bv;
      }
    }
  }
}

// ================== fallback path (ws too small): round-2 kernel ==================
#define CSTR 136
#define IWP 66

__global__ __launch_bounds__(512, 4) void conv_fb(
    const float* __restrict__ x, const unsigned short* __restrict__ w2,
    const float* __restrict__ bias, float* __restrict__ out) {
  __shared__ alignas(16) unsigned short xsf[4 * IWP * CSTR];

  const int ohp = blockIdx.x;
  const int n   = blockIdx.y;
  const int oh0 = ohp * 2;
  const int tid = threadIdx.x;

  {
    short8 zz = {0, 0, 0, 0, 0, 0, 0, 0};
    for (int i = tid; i < 4 * 10 * 17; i += 512) {
      int r = i / 170, rem = i % 170;
      int iw = 56 + rem / 17, g = rem % 17;
      *reinterpret_cast<short8*>(&xsf[(r * IWP + iw) * CSTR + g * 8]) = zz;
    }
  }
  for (int s = tid; s < 3584; s += 512) {
    int iw = s % 56;
    int t  = s / 56;
    int c8 = t & 15, r = t >> 4;
    const float* xp = x + (size_t)n * CIN * (H * W) + (oh0 + r) * W + iw;
    short8 v;
    #pragma unroll
    for (int j = 0; j < 8; ++j)
      v[j] = (short)f2bf(xp[(size_t)(c8 * 8 + j) * (H * W)]);
    *reinterpret_cast<short8*>(&xsf[(r * IWP + iw) * CSTR + c8 * 8]) = v;
  }
  __syncthreads();

  const int wid  = tid >> 6;
  const int lane = tid & 63;
  const int wm   = wid >> 1;
  const int wn   = wid & 1;
  const int l16  = lane & 15;
  const int cig  = lane >> 4;

  const int co_base = wm * 64;
  const int oh = oh0 + wn;

  floatx4 acc[4][4];
  #pragma unroll
  for (int m = 0; m < 4; ++m)
    #pragma unroll
    for (int nr = 0; nr < 4; ++nr)
      acc[m][nr] = (floatx4){0.f, 0.f, 0.f, 0.f};

  for (int kh = 0; kh < 3; ++kh) {
    const int row = wn + kh;
    #pragma unroll
    for (int ch = 0; ch < 4; ++ch) {
      const int bbase = (row * IWP + l16) * CSTR + ch * 32 + cig * 8;
      #pragma unroll
      for (int kw = 0; kw < 3; ++kw) {
        const unsigned short* wp =
            w2 + ((size_t)(((kh * 3 + kw) * 16 + (ch * 4 + cig)) * COUT + co_base + l16)) * 8;
        short8 a[4];
        #pragma unroll
        for (int m = 0; m < 4; ++m)
          a[m] = *reinterpret_cast<const short8*>(wp + m * 16 * 8);
        short8 b[4];
        #pragma unroll
        for (int nr = 0; nr < 4; ++nr)
          b[nr] = *reinterpret_cast<const short8*>(&xsf[bbase + (nr * 16 + kw) * CSTR]);
        #pragma unroll
        for (int m = 0; m < 4; ++m)
          #pragma unroll
          for (int nr = 0; nr < 4; ++nr)
            acc[m][nr] = __builtin_amdgcn_mfma_f32_16x16x32_bf16(a[m], b[nr], acc[m][nr], 0, 0, 0);
      }
    }
  }

  const int rowd = cig * 4;
  #pragma unroll
  for (int m = 0; m < 4; ++m) {
    #pragma unroll
    for (int reg = 0; reg < 4; ++reg) {
      int co = co_base + m * 16 + rowd + reg;
      float bv = bias[co];
      float* op = out + (((size_t)n * COUT + co) * OH + oh) * OW;
      #pragma unroll
      for (int nr = 0; nr < 4; ++nr) {
        int ow = nr * 16 + l16;
        if (ow < OW) op[ow] = acc[m][nr][reg] + bv;
      }
    }
  }
}

extern "C" void kernel_launch(void* const* d_in, const int* in_sizes, int n_in,
                              void* d_out, int out_size, void* d_ws, size_t ws_size,
                              hipStream_t stream) {
  (void)in_sizes; (void)n_in; (void)out_size;
  const float* x    = (const float*)d_in[0];
  const float* w    = (const float*)d_in[1];
  const float* bias = (const float*)d_in[2];
  float* out = (float*)d_out;

  const size_t W2_BYTES = (size_t)9 * 16 * COUT * 8 * 2;            // 589,824
  const size_t XB_BYTES = (size_t)32 * H * 896 * 8 * 2;             // 25,690,112
  unsigned short* w2 = (unsigned short*)d_ws;

  repack_w<<<dim3((COUT * CIN * 9 + 255) / 256), dim3(256), 0, stream>>>(w, w2);

  if (ws_size >= W2_BYTES + XB_BYTES) {
    unsigned short* xb = (unsigned short*)((char*)d_ws + W2_BYTES);
    repack_x<<<dim3(56, 32), dim3(256), 0, stream>>>(x, xb);
    conv2<<<dim3(864), dim3(512), 0, stream>>>(xb, w2, bias, out);
  } else {
    conv_fb<<<dim3(27, 32), dim3(512), 0, stream>>>(x, w2, bias, out);
  }
}